// Round 10
// baseline (626.754 us; speedup 1.0000x reference)
//
#include <hip/hip_runtime.h>

#define BB 512
#define V0 1024
#define V1 256
#define E0 8192
#define E1 2048

// ---------------- CSR build (deterministic) ----------------
__global__ void k_deg(const int* __restrict__ rows, int E, int* __restrict__ deg) {
    int t = blockIdx.x * 256 + threadIdx.x;
    if (t < E) atomicAdd(&deg[rows[t]], 1);
}

__global__ void k_scan(const int* __restrict__ deg, int* __restrict__ off, int V) {
    __shared__ int s[1024];
    int t = threadIdx.x;
    s[t] = (t < V) ? deg[t] : 0;
    __syncthreads();
    for (int d = 1; d < 1024; d <<= 1) {
        int val = (t >= d) ? s[t - d] : 0;
        __syncthreads();
        s[t] += val;
        __syncthreads();
    }
    if (t < V) off[t + 1] = s[t];
    if (t == 0) off[0] = 0;
}

// stable fill: edge e goes to off[row] + (#earlier edges with same row); packed (col,val)
__global__ void k_fillp(const int* __restrict__ rows, const int* __restrict__ cols,
                        const float* __restrict__ vals, int E,
                        const int* __restrict__ off, int2* __restrict__ epk) {
    __shared__ int rs[256];
    int e = blockIdx.x * 256 + threadIdx.x;
    int r = (e < E) ? rows[e] : -1;
    int rank = 0;
    for (int c0 = 0; c0 <= (int)blockIdx.x; ++c0) {
        __syncthreads();
        int idx = c0 * 256 + threadIdx.x;
        rs[threadIdx.x] = (idx < E) ? rows[idx] : -2;
        __syncthreads();
        int lim = e - c0 * 256;
        if (lim > 256) lim = 256;
        for (int j = 0; j < lim; ++j) rank += (rs[j] == r) ? 1 : 0;
    }
    if (e < E) {
        int p = off[r] + rank;
        epk[p] = make_int2(cols[e], __float_as_int(vals[e]));
    }
}

// ---------------- fused cheby conv, batch-major, feature-major LDS (padded) ----------------
// Structure = R6 (verified): feature-major slab xsA[3*FH][NCP], Wl panels, acc[4][OW]
// GEMM microtile. ONE change: edge metadata (col,val) preloaded into registers ONCE
// (NPRE slots, group-of-4 guards, tail loop for deg>NPRE) instead of re-loading
// scol/sval from global on every gather pass (was 128-256 scattered loads/thread).
// MW = min waves/EU for __launch_bounds__ (pins VGPR cap; prevents the 64-cap spill).
template <int V, int NB, int FIN, int FH, int FOUT, int POOL, int NPRE, int MW>
__global__ __launch_bounds__(NB * V, MW) void k_conv(
    const float* __restrict__ xin, const float* __restrict__ W,
    const float* __restrict__ bias, float* __restrict__ out,
    const int* __restrict__ off, const int2* __restrict__ epk) {
    constexpr int NPH = FIN / FH;
    constexpr int OW = FOUT / 4;   // outputs per thread
    constexpr int NC = NB * V;     // LDS columns (== blockDim.x)
    constexpr int NCP = NC + 4;    // padded column stride (16B aligned)
    __shared__ float xsA[3 * FH * NCP];
    __shared__ float Wl[3 * FH * FOUT];

    const int t = threadIdx.x;
    const int bb = (NB == 1) ? 0 : (t / V);
    const int vloc = (NB == 1) ? t : (t - bb * V);
    const int b = blockIdx.x * NB + bb;
    const int vt = vloc >> 2;
    const int ot = vloc & 3;
    const int o0 = ot * OW;
    const int colg = bb * V;

    const int s0 = off[vloc];
    const int e0 = off[vloc + 1];
    const int deg = e0 - s0;

    // ---- edge preload (once per kernel; clamped index, zero-weight padding)
    int pcol[NPRE];
    float pw[NPRE];
#pragma unroll
    for (int i = 0; i < NPRE; ++i) {
        int2 e = epk[s0 + ((i < deg) ? i : 0)];
        pcol[i] = colg + e.x;
        pw[i] = (i < deg) ? __int_as_float(e.y) : 0.f;
    }

    float acc[4][OW];
#pragma unroll
    for (int i = 0; i < 4; ++i)
#pragma unroll
        for (int o = 0; o < OW; ++o) acc[i][o] = 0.f;

// gather pass: r = L * slab[RB..RB+FH) -> slab[ROUT..ROUT+FH) at own column
#define GATHER(RB, ROUT)                                                      \
    {                                                                         \
        float r_[FH];                                                         \
        _Pragma("unroll") for (int f = 0; f < FH; ++f) r_[f] = 0.f;           \
        _Pragma("unroll") for (int g = 0; g < NPRE / 4; ++g) {                \
            if (deg > 4 * g) {                                                \
                _Pragma("unroll") for (int i = 4 * g; i < 4 * g + 4; ++i) {   \
                    _Pragma("unroll") for (int f = 0; f < FH; ++f)            \
                        r_[f] += pw[i] * xsA[((RB) + f) * NCP + pcol[i]];     \
                }                                                             \
            }                                                                 \
        }                                                                     \
        if (deg > NPRE) {                                                     \
            for (int p = s0 + NPRE; p < e0; ++p) {                            \
                int2 e_ = epk[p];                                             \
                float w_ = __int_as_float(e_.y);                              \
                int c_ = colg + e_.x;                                         \
                _Pragma("unroll") for (int f = 0; f < FH; ++f)                \
                    r_[f] += w_ * xsA[((RB) + f) * NCP + c_];                 \
            }                                                                 \
        }                                                                     \
        _Pragma("unroll") for (int f = 0; f < FH; ++f)                        \
            xsA[((ROUT) + f) * NCP + colg + vloc] = r_[f];                    \
    }

    for (int ph = 0; ph < NPH; ++ph) {
        // ---- transformed weight panels for this feature slice (k-major [k][o])
        for (int idx = t; idx < FH * FOUT; idx += NC) {
            int f = idx / FOUT, o = idx - f * FOUT;
            int fg = ph * FH + f;
            float w0 = W[o * (3 * FIN) + fg * 3 + 0];
            float w1 = W[o * (3 * FIN) + fg * 3 + 1];
            float w2 = W[o * (3 * FIN) + fg * 3 + 2];
            Wl[f * FOUT + o] = w0 - w2;
            Wl[(FH + f) * FOUT + o] = w1;
            Wl[(2 * FH + f) * FOUT + o] = 2.f * w2;
        }
        // ---- stage x0 feature slice, feature-major (padded stride)
        if constexpr (FH == 3) {
#pragma unroll
            for (int f = 0; f < 3; ++f)
                xsA[f * NCP + colg + vloc] = xin[((size_t)b * V + vloc) * 3 + f];
        } else {
#pragma unroll
            for (int j = 0; j < FH / 4; ++j) {
                float4 q = *(const float4*)(xin + ((size_t)b * V + vloc) * FIN + ph * FH + 4 * j);
                xsA[(4 * j + 0) * NCP + colg + vloc] = q.x;
                xsA[(4 * j + 1) * NCP + colg + vloc] = q.y;
                xsA[(4 * j + 2) * NCP + colg + vloc] = q.z;
                xsA[(4 * j + 3) * NCP + colg + vloc] = q.w;
            }
        }
        __syncthreads();
        // ---- x1 = L x0
        GATHER(0, FH)
        __syncthreads();
        // ---- x2raw = L x1
        GATHER(FH, 2 * FH)
        __syncthreads();
        // ---- GEMM accumulate: K = 3*FH
        {
            const int a0 = colg + 4 * vt;
#pragma unroll 4
            for (int k = 0; k < 3 * FH; ++k) {
                float4 a = *(const float4*)&xsA[k * NCP + a0];
                float av[4] = {a.x, a.y, a.z, a.w};
#pragma unroll
                for (int j = 0; j < OW / 4; ++j) {
                    float4 wv = *(const float4*)&Wl[k * FOUT + o0 + 4 * j];
#pragma unroll
                    for (int i = 0; i < 4; ++i) {
                        acc[i][4 * j + 0] += av[i] * wv.x;
                        acc[i][4 * j + 1] += av[i] * wv.y;
                        acc[i][4 * j + 2] += av[i] * wv.z;
                        acc[i][4 * j + 3] += av[i] * wv.w;
                    }
                }
            }
        }
        __syncthreads();  // protect LDS before next phase overwrites
    }
#undef GATHER

    // ---- epilogue
    if constexpr (POOL == 0) {
#pragma unroll
        for (int i = 0; i < 4; ++i) {
            float* orow = out + ((size_t)b * V + 4 * vt + i) * FOUT + o0;
#pragma unroll
            for (int j = 0; j < OW / 4; ++j) {
                float4 st;
                st.x = acc[i][4 * j + 0] + bias[o0 + 4 * j + 0];
                st.y = acc[i][4 * j + 1] + bias[o0 + 4 * j + 1];
                st.z = acc[i][4 * j + 2] + bias[o0 + 4 * j + 2];
                st.w = acc[i][4 * j + 3] + bias[o0 + 4 * j + 3];
                ((float4*)orow)[j] = st;
            }
        }
    } else {
        float* orow = out + ((size_t)b * (V / 4) + vt) * FOUT + o0;
#pragma unroll
        for (int j = 0; j < OW / 4; ++j) {
            float4 st;
#pragma unroll
            for (int q = 0; q < 4; ++q) {
                int o = 4 * j + q;
                float m = fmaxf(fmaxf(acc[0][o], acc[1][o]), fmaxf(acc[2][o], acc[3][o]));
                ((float*)&st)[q] = m + bias[o0 + o];
            }
            ((float4*)orow)[j] = st;
        }
    }
}

// ---------------- FC1: C[512,512] = A[512,4096] * W[512,4096]^T, split-K=16 ----------------
__global__ __launch_bounds__(256) void k_fc1(const float* __restrict__ A,
                                             const float* __restrict__ W,
                                             float* __restrict__ part) {
    __shared__ float As[16][128];
    __shared__ float Bs[16][128];
    const int tid = threadIdx.x;
    const int bm = blockIdx.x, bn = blockIdx.y, bz = blockIdx.z;
    const int m0 = (tid >> 4) << 3;
    const int n0 = (tid & 15) << 3;
    float acc[8][8];
#pragma unroll
    for (int i = 0; i < 8; ++i)
#pragma unroll
        for (int j = 0; j < 8; ++j) acc[i][j] = 0.f;
    const int r = tid >> 1;
    const int c8 = (tid & 1) << 3;
    const float* Ar = A + (size_t)(bm * 128 + r) * 4096 + bz * 256 + c8;
    const float* Wr = W + (size_t)(bn * 128 + r) * 4096 + bz * 256 + c8;
    for (int kt = 0; kt < 256; kt += 16) {
        float4 a0 = *(const float4*)(Ar + kt);
        float4 a1 = *(const float4*)(Ar + kt + 4);
        float4 w0 = *(const float4*)(Wr + kt);
        float4 w1 = *(const float4*)(Wr + kt + 4);
        __syncthreads();
        As[c8 + 0][r] = a0.x; As[c8 + 1][r] = a0.y; As[c8 + 2][r] = a0.z; As[c8 + 3][r] = a0.w;
        As[c8 + 4][r] = a1.x; As[c8 + 5][r] = a1.y; As[c8 + 6][r] = a1.z; As[c8 + 7][r] = a1.w;
        Bs[c8 + 0][r] = w0.x; Bs[c8 + 1][r] = w0.y; Bs[c8 + 2][r] = w0.z; Bs[c8 + 3][r] = w0.w;
        Bs[c8 + 4][r] = w1.x; Bs[c8 + 5][r] = w1.y; Bs[c8 + 6][r] = w1.z; Bs[c8 + 7][r] = w1.w;
        __syncthreads();
#pragma unroll
        for (int k = 0; k < 16; ++k) {
            float am[8], bn_[8];
            *(float4*)&am[0] = *(const float4*)&As[k][m0];
            *(float4*)&am[4] = *(const float4*)&As[k][m0 + 4];
            *(float4*)&bn_[0] = *(const float4*)&Bs[k][n0];
            *(float4*)&bn_[4] = *(const float4*)&Bs[k][n0 + 4];
#pragma unroll
            for (int i = 0; i < 8; ++i)
#pragma unroll
                for (int j = 0; j < 8; ++j) acc[i][j] += am[i] * bn_[j];
        }
    }
    float* P = part + ((size_t)bz * 512 + bm * 128 + m0) * 512 + bn * 128 + n0;
#pragma unroll
    for (int i = 0; i < 8; ++i) {
        float4 s0 = {acc[i][0], acc[i][1], acc[i][2], acc[i][3]};
        float4 s1 = {acc[i][4], acc[i][5], acc[i][6], acc[i][7]};
        *(float4*)(P + i * 512) = s0;
        *(float4*)(P + i * 512 + 4) = s1;
    }
}

__global__ void k_fc1red(const float* __restrict__ part, const float* __restrict__ bias,
                         float* __restrict__ out) {
    int t = blockIdx.x * 256 + threadIdx.x;  // 512*512
    float s = bias[t & 511];
#pragma unroll
    for (int z = 0; z < 16; ++z) s += part[(size_t)z * 262144 + t];
    out[t] = s;
}

// ---------------- FC2: out[512,63] ----------------
__global__ void k_fc2(const float* __restrict__ X, const float* __restrict__ W,
                      const float* __restrict__ bias, float* __restrict__ out) {
    int b = blockIdx.x, c = threadIdx.x;
    if (c >= 63) return;
    const float4* xr = (const float4*)(X + b * 512);
    const float4* wr = (const float4*)(W + c * 512);
    float s = 0.f;
    for (int k = 0; k < 128; ++k) {
        float4 xv = xr[k], wv = wr[k];
        s += xv.x * wv.x + xv.y * wv.y + xv.z * wv.z + xv.w * wv.w;
    }
    out[b * 63 + c] = s + bias[c];
}

extern "C" void kernel_launch(void* const* d_in, const int* in_sizes, int n_in,
                              void* d_out, int out_size, void* d_ws, size_t ws_size,
                              hipStream_t stream) {
    const float* x = (const float*)d_in[0];
    const int* rows0 = (const int*)d_in[1];
    const int* cols0 = (const int*)d_in[2];
    const float* vals0 = (const float*)d_in[3];
    const int* rows1 = (const int*)d_in[4];
    const int* cols1 = (const int*)d_in[5];
    const float* vals1 = (const float*)d_in[6];
    const float* W0 = (const float*)d_in[7];  const float* b0 = (const float*)d_in[8];
    const float* W1 = (const float*)d_in[9];  const float* b1 = (const float*)d_in[10];
    const float* W2 = (const float*)d_in[11]; const float* b2 = (const float*)d_in[12];
    const float* W3 = (const float*)d_in[13]; const float* b3 = (const float*)d_in[14];
    const float* fcW1 = (const float*)d_in[15]; const float* fcb1 = (const float*)d_in[16];
    const float* fcW2 = (const float*)d_in[17]; const float* fcb2 = (const float*)d_in[18];
    float* out = (float*)d_out;

    float* wsf = (float*)d_ws;
    // small region
    int* off0 = (int*)(wsf + 0);          // 1025
    int* off1 = (int*)(wsf + 1088);       // 257
    int* deg0 = (int*)(wsf + 1408);       // 1024
    int* deg1 = (int*)(wsf + 2432);       // 256
    int2* epk0 = (int2*)(wsf + 4096);     // 8192 int2 -> [4096, 20480)
    int2* epk1 = (int2*)(wsf + 20480);    // 2048 int2 -> [20480, 24576)

    float* A1  = wsf + 65536;             // 16,777,216  [B,1024,32]
    float* P1  = A1 + 16777216;           //  4,194,304  [B,256,32]
    float* A3  = P1 + 4194304;            //  8,388,608  [B,256,64]
    float* FCB = A3 + 8388608;            //  2,097,152  [B,4096]
    float* PART = FCB + 2097152;          //  4,194,304  [16,512,512]
    float* FC1O = PART + 4194304;         //    262,144  [512,512]
    (void)in_sizes; (void)n_in; (void)out_size; (void)ws_size;

    hipMemsetAsync(wsf + 1408, 0, 1280 * 4, stream);
    k_deg<<<E0 / 256, 256, 0, stream>>>(rows0, E0, deg0);
    k_deg<<<E1 / 256, 256, 0, stream>>>(rows1, E1, deg1);
    k_scan<<<1, 1024, 0, stream>>>(deg0, off0, V0);
    k_scan<<<1, 1024, 0, stream>>>(deg1, off1, V1);
    k_fillp<<<E0 / 256, 256, 0, stream>>>(rows0, cols0, vals0, E0, off0, epk0);
    k_fillp<<<E1 / 256, 256, 0, stream>>>(rows1, cols1, vals1, E1, off1, epk1);

    // conv1: level0, 3->32             1024 thr, LDS ~13 KB, VGPR cap 128
    k_conv<V0, 1, 3, 3, 32, 0, 16, 4><<<BB, 1024, 0, stream>>>(x, W0, b0, A1, off0, epk0);
    // conv2+pool: level0, 32->32, FH=8, 1024 thr, LDS ~102 KB, VGPR cap 128
    k_conv<V0, 1, 32, 8, 32, 1, 16, 4><<<BB, 1024, 0, stream>>>(A1, W1, b1, P1, off0, epk0);
    // conv3: level1, 32->64            256 thr, 512 blocks, LDS ~31 KB, VGPR cap 256
    k_conv<V1, 1, 32, 8, 64, 0, 16, 2><<<BB, 256, 0, stream>>>(P1, W2, b2, A3, off1, epk1);
    // conv4+pool: level1, 64->64       256 thr, 512 blocks, LDS ~31 KB, VGPR cap 256
    k_conv<V1, 1, 64, 8, 64, 1, 16, 2><<<BB, 256, 0, stream>>>(A3, W3, b3, FCB, off1, epk1);

    // head (FCB is [B, 4096] in reference order)
    k_fc1<<<dim3(4, 4, 16), 256, 0, stream>>>(FCB, fcW1, PART);
    k_fc1red<<<1024, 256, 0, stream>>>(PART, fcb1, FC1O);
    k_fc2<<<BB, 64, 0, stream>>>(FC1O, fcW2, fcb2, out);
}

// Round 11
// 490.995 us; speedup vs baseline: 1.2765x; 1.2765x over previous
//
#include <hip/hip_runtime.h>

#define BB 512
#define V0 1024
#define V1 256
#define E0 8192
#define E1 2048

// ---------------- CSR build (deterministic) ----------------
__global__ void k_deg(const int* __restrict__ rows, int E, int* __restrict__ deg) {
    int t = blockIdx.x * 256 + threadIdx.x;
    if (t < E) atomicAdd(&deg[rows[t]], 1);
}

__global__ void k_scan(const int* __restrict__ deg, int* __restrict__ off, int V) {
    __shared__ int s[1024];
    int t = threadIdx.x;
    s[t] = (t < V) ? deg[t] : 0;
    __syncthreads();
    for (int d = 1; d < 1024; d <<= 1) {
        int val = (t >= d) ? s[t - d] : 0;
        __syncthreads();
        s[t] += val;
        __syncthreads();
    }
    if (t < V) off[t + 1] = s[t];
    if (t == 0) off[0] = 0;
}

// stable fill: edge e goes to off[row] + (#earlier edges with same row); packed (col,val)
__global__ void k_fillp(const int* __restrict__ rows, const int* __restrict__ cols,
                        const float* __restrict__ vals, int E,
                        const int* __restrict__ off, int2* __restrict__ epk) {
    __shared__ int rs[256];
    int e = blockIdx.x * 256 + threadIdx.x;
    int r = (e < E) ? rows[e] : -1;
    int rank = 0;
    for (int c0 = 0; c0 <= (int)blockIdx.x; ++c0) {
        __syncthreads();
        int idx = c0 * 256 + threadIdx.x;
        rs[threadIdx.x] = (idx < E) ? rows[idx] : -2;
        __syncthreads();
        int lim = e - c0 * 256;
        if (lim > 256) lim = 256;
        for (int j = 0; j < lim; ++j) rank += (rs[j] == r) ? 1 : 0;
    }
    if (e < E) {
        int p = off[r] + rank;
        epk[p] = make_int2(cols[e], __float_as_int(vals[e]));
    }
}

// ---------------- fused cheby conv, batch-major, feature-major LDS (padded) ----------------
// Structure = R6 (verified 508us). Changes vs R6: (a) edge records packed int2
// (1 dwordx2 load per edge instead of 2 scattered dwords), (b) 2-deep software
// prefetch in the edge loop (next edge load overlaps current edge's LDS+FMA work).
// No preload arrays, no wide register structures (1024-thr blocks cap at 64 VGPR).
// MW: __launch_bounds__ min-blocks arg; 0 = omit (default cap).
template <int V, int NB, int FIN, int FH, int FOUT, int POOL, int MW>
__global__ __launch_bounds__(NB * V, MW) void k_conv(
    const float* __restrict__ xin, const float* __restrict__ W,
    const float* __restrict__ bias, float* __restrict__ out,
    const int* __restrict__ off, const int2* __restrict__ epk) {
    constexpr int NPH = FIN / FH;
    constexpr int OW = FOUT / 4;   // outputs per thread
    constexpr int NC = NB * V;     // LDS columns (== blockDim.x)
    constexpr int NCP = NC + 4;    // padded column stride (16B aligned)
    __shared__ float xsA[3 * FH * NCP];
    __shared__ float Wl[3 * FH * FOUT];

    const int t = threadIdx.x;
    const int bb = (NB == 1) ? 0 : (t / V);
    const int vloc = (NB == 1) ? t : (t - bb * V);
    const int b = blockIdx.x * NB + bb;
    const int vt = vloc >> 2;
    const int ot = vloc & 3;
    const int o0 = ot * OW;
    const int colg = bb * V;

    const int s0 = off[vloc];
    const int e0 = off[vloc + 1];

    float acc[4][OW];
#pragma unroll
    for (int i = 0; i < 4; ++i)
#pragma unroll
        for (int o = 0; o < OW; ++o) acc[i][o] = 0.f;

// gather pass with 2-deep edge prefetch: r = L * slab[RB..) -> slab[ROUT..) at own col
#define GATHER(RB, ROUT)                                                      \
    {                                                                         \
        float r_[FH];                                                         \
        _Pragma("unroll") for (int f = 0; f < FH; ++f) r_[f] = 0.f;           \
        int2 e_ = epk[s0];                                                    \
        for (int p = s0; p < e0; ++p) {                                       \
            int2 cur_ = e_;                                                   \
            if (p + 1 < e0) e_ = epk[p + 1];                                  \
            float w_ = __int_as_float(cur_.y);                                \
            int c_ = colg + cur_.x;                                           \
            _Pragma("unroll") for (int f = 0; f < FH; ++f)                    \
                r_[f] += w_ * xsA[((RB) + f) * NCP + c_];                     \
        }                                                                     \
        _Pragma("unroll") for (int f = 0; f < FH; ++f)                        \
            xsA[((ROUT) + f) * NCP + colg + vloc] = r_[f];                    \
    }

    for (int ph = 0; ph < NPH; ++ph) {
        // ---- transformed weight panels for this feature slice (k-major [k][o])
        for (int idx = t; idx < FH * FOUT; idx += NC) {
            int f = idx / FOUT, o = idx - f * FOUT;
            int fg = ph * FH + f;
            float w0 = W[o * (3 * FIN) + fg * 3 + 0];
            float w1 = W[o * (3 * FIN) + fg * 3 + 1];
            float w2 = W[o * (3 * FIN) + fg * 3 + 2];
            Wl[f * FOUT + o] = w0 - w2;
            Wl[(FH + f) * FOUT + o] = w1;
            Wl[(2 * FH + f) * FOUT + o] = 2.f * w2;
        }
        // ---- stage x0 feature slice, feature-major (padded stride)
        if constexpr (FH == 3) {
#pragma unroll
            for (int f = 0; f < 3; ++f)
                xsA[f * NCP + colg + vloc] = xin[((size_t)b * V + vloc) * 3 + f];
        } else {
#pragma unroll
            for (int j = 0; j < FH / 4; ++j) {
                float4 q = *(const float4*)(xin + ((size_t)b * V + vloc) * FIN + ph * FH + 4 * j);
                xsA[(4 * j + 0) * NCP + colg + vloc] = q.x;
                xsA[(4 * j + 1) * NCP + colg + vloc] = q.y;
                xsA[(4 * j + 2) * NCP + colg + vloc] = q.z;
                xsA[(4 * j + 3) * NCP + colg + vloc] = q.w;
            }
        }
        __syncthreads();
        // ---- x1 = L x0
        GATHER(0, FH)
        __syncthreads();
        // ---- x2raw = L x1
        GATHER(FH, 2 * FH)
        __syncthreads();
        // ---- GEMM accumulate: K = 3*FH
        {
            const int a0 = colg + 4 * vt;
#pragma unroll 4
            for (int k = 0; k < 3 * FH; ++k) {
                float4 a = *(const float4*)&xsA[k * NCP + a0];
                float av[4] = {a.x, a.y, a.z, a.w};
#pragma unroll
                for (int j = 0; j < OW / 4; ++j) {
                    float4 wv = *(const float4*)&Wl[k * FOUT + o0 + 4 * j];
#pragma unroll
                    for (int i = 0; i < 4; ++i) {
                        acc[i][4 * j + 0] += av[i] * wv.x;
                        acc[i][4 * j + 1] += av[i] * wv.y;
                        acc[i][4 * j + 2] += av[i] * wv.z;
                        acc[i][4 * j + 3] += av[i] * wv.w;
                    }
                }
            }
        }
        __syncthreads();  // protect LDS before next phase overwrites
    }
#undef GATHER

    // ---- epilogue
    if constexpr (POOL == 0) {
#pragma unroll
        for (int i = 0; i < 4; ++i) {
            float* orow = out + ((size_t)b * V + 4 * vt + i) * FOUT + o0;
#pragma unroll
            for (int j = 0; j < OW / 4; ++j) {
                float4 st;
                st.x = acc[i][4 * j + 0] + bias[o0 + 4 * j + 0];
                st.y = acc[i][4 * j + 1] + bias[o0 + 4 * j + 1];
                st.z = acc[i][4 * j + 2] + bias[o0 + 4 * j + 2];
                st.w = acc[i][4 * j + 3] + bias[o0 + 4 * j + 3];
                ((float4*)orow)[j] = st;
            }
        }
    } else {
        float* orow = out + ((size_t)b * (V / 4) + vt) * FOUT + o0;
#pragma unroll
        for (int j = 0; j < OW / 4; ++j) {
            float4 st;
#pragma unroll
            for (int q = 0; q < 4; ++q) {
                int o = 4 * j + q;
                float m = fmaxf(fmaxf(acc[0][o], acc[1][o]), fmaxf(acc[2][o], acc[3][o]));
                ((float*)&st)[q] = m + bias[o0 + o];
            }
            ((float4*)orow)[j] = st;
        }
    }
}

// ---------------- FC1: C[512,512] = A[512,4096] * W[512,4096]^T, split-K=16 ----------------
__global__ __launch_bounds__(256) void k_fc1(const float* __restrict__ A,
                                             const float* __restrict__ W,
                                             float* __restrict__ part) {
    __shared__ float As[16][128];
    __shared__ float Bs[16][128];
    const int tid = threadIdx.x;
    const int bm = blockIdx.x, bn = blockIdx.y, bz = blockIdx.z;
    const int m0 = (tid >> 4) << 3;
    const int n0 = (tid & 15) << 3;
    float acc[8][8];
#pragma unroll
    for (int i = 0; i < 8; ++i)
#pragma unroll
        for (int j = 0; j < 8; ++j) acc[i][j] = 0.f;
    const int r = tid >> 1;
    const int c8 = (tid & 1) << 3;
    const float* Ar = A + (size_t)(bm * 128 + r) * 4096 + bz * 256 + c8;
    const float* Wr = W + (size_t)(bn * 128 + r) * 4096 + bz * 256 + c8;
    for (int kt = 0; kt < 256; kt += 16) {
        float4 a0 = *(const float4*)(Ar + kt);
        float4 a1 = *(const float4*)(Ar + kt + 4);
        float4 w0 = *(const float4*)(Wr + kt);
        float4 w1 = *(const float4*)(Wr + kt + 4);
        __syncthreads();
        As[c8 + 0][r] = a0.x; As[c8 + 1][r] = a0.y; As[c8 + 2][r] = a0.z; As[c8 + 3][r] = a0.w;
        As[c8 + 4][r] = a1.x; As[c8 + 5][r] = a1.y; As[c8 + 6][r] = a1.z; As[c8 + 7][r] = a1.w;
        Bs[c8 + 0][r] = w0.x; Bs[c8 + 1][r] = w0.y; Bs[c8 + 2][r] = w0.z; Bs[c8 + 3][r] = w0.w;
        Bs[c8 + 4][r] = w1.x; Bs[c8 + 5][r] = w1.y; Bs[c8 + 6][r] = w1.z; Bs[c8 + 7][r] = w1.w;
        __syncthreads();
#pragma unroll
        for (int k = 0; k < 16; ++k) {
            float am[8], bn_[8];
            *(float4*)&am[0] = *(const float4*)&As[k][m0];
            *(float4*)&am[4] = *(const float4*)&As[k][m0 + 4];
            *(float4*)&bn_[0] = *(const float4*)&Bs[k][n0];
            *(float4*)&bn_[4] = *(const float4*)&Bs[k][n0 + 4];
#pragma unroll
            for (int i = 0; i < 8; ++i)
#pragma unroll
                for (int j = 0; j < 8; ++j) acc[i][j] += am[i] * bn_[j];
        }
    }
    float* P = part + ((size_t)bz * 512 + bm * 128 + m0) * 512 + bn * 128 + n0;
#pragma unroll
    for (int i = 0; i < 8; ++i) {
        float4 s0 = {acc[i][0], acc[i][1], acc[i][2], acc[i][3]};
        float4 s1 = {acc[i][4], acc[i][5], acc[i][6], acc[i][7]};
        *(float4*)(P + i * 512) = s0;
        *(float4*)(P + i * 512 + 4) = s1;
    }
}

__global__ void k_fc1red(const float* __restrict__ part, const float* __restrict__ bias,
                         float* __restrict__ out) {
    int t = blockIdx.x * 256 + threadIdx.x;  // 512*512
    float s = bias[t & 511];
#pragma unroll
    for (int z = 0; z < 16; ++z) s += part[(size_t)z * 262144 + t];
    out[t] = s;
}

// ---------------- FC2: out[512,63] ----------------
__global__ void k_fc2(const float* __restrict__ X, const float* __restrict__ W,
                      const float* __restrict__ bias, float* __restrict__ out) {
    int b = blockIdx.x, c = threadIdx.x;
    if (c >= 63) return;
    const float4* xr = (const float4*)(X + b * 512);
    const float4* wr = (const float4*)(W + c * 512);
    float s = 0.f;
    for (int k = 0; k < 128; ++k) {
        float4 xv = xr[k], wv = wr[k];
        s += xv.x * wv.x + xv.y * wv.y + xv.z * wv.z + xv.w * wv.w;
    }
    out[b * 63 + c] = s + bias[c];
}

extern "C" void kernel_launch(void* const* d_in, const int* in_sizes, int n_in,
                              void* d_out, int out_size, void* d_ws, size_t ws_size,
                              hipStream_t stream) {
    const float* x = (const float*)d_in[0];
    const int* rows0 = (const int*)d_in[1];
    const int* cols0 = (const int*)d_in[2];
    const float* vals0 = (const float*)d_in[3];
    const int* rows1 = (const int*)d_in[4];
    const int* cols1 = (const int*)d_in[5];
    const float* vals1 = (const float*)d_in[6];
    const float* W0 = (const float*)d_in[7];  const float* b0 = (const float*)d_in[8];
    const float* W1 = (const float*)d_in[9];  const float* b1 = (const float*)d_in[10];
    const float* W2 = (const float*)d_in[11]; const float* b2 = (const float*)d_in[12];
    const float* W3 = (const float*)d_in[13]; const float* b3 = (const float*)d_in[14];
    const float* fcW1 = (const float*)d_in[15]; const float* fcb1 = (const float*)d_in[16];
    const float* fcW2 = (const float*)d_in[17]; const float* fcb2 = (const float*)d_in[18];
    float* out = (float*)d_out;

    float* wsf = (float*)d_ws;
    // small region
    int* off0 = (int*)(wsf + 0);          // 1025
    int* off1 = (int*)(wsf + 1088);       // 257
    int* deg0 = (int*)(wsf + 1408);       // 1024
    int* deg1 = (int*)(wsf + 2432);       // 256
    int2* epk0 = (int2*)(wsf + 4096);     // 8192 int2 -> [4096, 20480)
    int2* epk1 = (int2*)(wsf + 20480);    // 2048 int2 -> [20480, 24576)

    float* A1  = wsf + 65536;             // 16,777,216  [B,1024,32]
    float* P1  = A1 + 16777216;           //  4,194,304  [B,256,32]
    float* A3  = P1 + 4194304;            //  8,388,608  [B,256,64]
    float* FCB = A3 + 8388608;            //  2,097,152  [B,4096]
    float* PART = FCB + 2097152;          //  4,194,304  [16,512,512]
    float* FC1O = PART + 4194304;         //    262,144  [512,512]
    (void)in_sizes; (void)n_in; (void)out_size; (void)ws_size;

    hipMemsetAsync(wsf + 1408, 0, 1280 * 4, stream);
    k_deg<<<E0 / 256, 256, 0, stream>>>(rows0, E0, deg0);
    k_deg<<<E1 / 256, 256, 0, stream>>>(rows1, E1, deg1);
    k_scan<<<1, 1024, 0, stream>>>(deg0, off0, V0);
    k_scan<<<1, 1024, 0, stream>>>(deg1, off1, V1);
    k_fillp<<<E0 / 256, 256, 0, stream>>>(rows0, cols0, vals0, E0, off0, epk0);
    k_fillp<<<E1 / 256, 256, 0, stream>>>(rows1, cols1, vals1, E1, off1, epk1);

    // conv1: level0, 3->32             1024 thr, LDS ~38 KB, default bounds
    k_conv<V0, 1, 3, 3, 32, 0, 1><<<BB, 1024, 0, stream>>>(x, W0, b0, A1, off0, epk0);
    // conv2+pool: level0, 32->32, FH=8, 1024 thr, LDS ~102 KB, default-ish bounds
    k_conv<V0, 1, 32, 8, 32, 1, 1><<<BB, 1024, 0, stream>>>(A1, W1, b1, P1, off0, epk0);
    // conv3: level1, 32->64            256 thr, 512 blocks, LDS ~31 KB, cap 256 VGPR
    k_conv<V1, 1, 32, 8, 64, 0, 2><<<BB, 256, 0, stream>>>(P1, W2, b2, A3, off1, epk1);
    // conv4+pool: level1, 64->64       256 thr, 512 blocks, LDS ~31 KB, cap 256 VGPR
    k_conv<V1, 1, 64, 8, 64, 1, 2><<<BB, 256, 0, stream>>>(A3, W3, b3, FCB, off1, epk1);

    // head (FCB is [B, 4096] in reference order)
    k_fc1<<<dim3(4, 4, 16), 256, 0, stream>>>(FCB, fcW1, PART);
    k_fc1red<<<1024, 256, 0, stream>>>(PART, fcb1, FC1O);
    k_fc2<<<BB, 64, 0, stream>>>(FC1O, fcW2, fcb2, out);
}